// Round 5
// baseline (270.159 us; speedup 1.0000x reference)
//
#include <hip/hip_runtime.h>

#define BB 4096
#define SS 200
#define DD 128
#define HH 64
#define NT 13            // 13 tiles of 16 rows (208 padded)
#define OUTW (DD + 1)

typedef __attribute__((ext_vector_type(4))) float f32x4;
typedef __attribute__((ext_vector_type(8))) __bf16 bf16x8;

__device__ __forceinline__ short f2b(float f) {        // f32 -> bf16 (RNE)
  unsigned int u = __float_as_uint(f);
  unsigned int r = (u + 0x7FFFu + ((u >> 16) & 1u)) >> 16;
  return (short)r;
}

// ---------------- setup1: P = pos@Wp, We -> MFMA B-frag order, mask dtype probe ----
__global__ void setup_kernel(const float* __restrict__ pos,
                             const float* __restrict__ Wp,
                             const float* __restrict__ We,
                             const void* __restrict__ maskv,
                             float* __restrict__ Pmat,
                             short* __restrict__ Bfrag,
                             int* __restrict__ flag) {
  __shared__ int anyf[4];
  const int blk = blockIdx.x;
  const int t = threadIdx.x;
  if (blk < SS) {
    if (t < HH) {
      float acc = 0.f;
      #pragma unroll 8
      for (int d = 0; d < DD; ++d) acc = fmaf(pos[blk * DD + d], Wp[d * HH + t], acc);
      Pmat[blk * HH + t] = acc;
    }
  } else if (blk == SS) {
    // Bfrag[((ct*4+kt)*64+lane)*8 + j] = bf16(We[kt*32 + 8*(lane>>4) + j][ct*16 + (lane&15)])
    for (int id = t; id < 1024; id += 256) {
      int lane = id & 63;
      int kt = (id >> 6) & 3;
      int ct = id >> 8;
      int kbase = kt * 32 + 8 * (lane >> 4);
      int n = ct * 16 + (lane & 15);
      short* dst = Bfrag + id * 8;
      #pragma unroll
      for (int j = 0; j < 8; ++j) dst[j] = f2b(We[(kbase + j) * HH + n]);
    }
  } else {
    // mask dtype probe: bool8 has nonzero bytes at positions %4!=0; int32(0/1) does not
    const unsigned char* mb = (const unsigned char*)maskv;
    int local = 0;
    for (int i = t; i < 4096; i += 256)
      if ((i & 3) != 0 && mb[i] != 0) local = 1;
    unsigned long long bal = __ballot(local != 0);
    if ((t & 63) == 0) anyf[t >> 6] = (bal != 0ull) ? 1 : 0;
    __syncthreads();
    if (t == 0) *flag = (anyf[0] | anyf[1] | anyf[2] | anyf[3]);
  }
}

// ---------------- setup2: swizzle Pmat into per-lane-contiguous layout -------------
// Psw[(((t*4+lg)*16+lr)*16 + ct*4 + r)] = Pmat[min(t*16+4lg+r,199)][16ct+lr]
__global__ void swizzle_kernel(const float* __restrict__ Pmat, float* __restrict__ Psw) {
  const int t = blockIdx.x;                 // tile 0..12
  const int tid = threadIdx.x;              // 256
  const int lg = tid >> 6, lr = (tid >> 2) & 15, ct = tid & 3;
  f32x4 v;
  #pragma unroll
  for (int r = 0; r < 4; ++r) {
    int s = t * 16 + 4 * lg + r;
    if (s >= SS) s = SS - 1;
    v[r] = Pmat[s * HH + ct * 16 + lr];
  }
  *(f32x4*)&Psw[((t * 4 + lg) * 16 + lr) * 16 + ct * 4] = v;
}

// ---------------- fused: one BLOCK per row, wave w owns tiles {w, w+4, w+8, w+12} ---
__global__ __launch_bounds__(256, 4) void fused_kernel(
    const float* __restrict__ Xs, const float* __restrict__ Xi,
    const void* __restrict__ maskv, const float* __restrict__ Wc,
    const float* __restrict__ zv, const float* __restrict__ Psw,
    const short* __restrict__ Bfrag, const int* __restrict__ flagp,
    float* __restrict__ out) {
  __shared__ __align__(16) short bf_lds[16 * 64 * 8];   // 16 KB We B-fragments
  __shared__ float psum[4][DD];                         // per-wave weighted-sum partials
  __shared__ float uw[4], sw[4];

  const int t = threadIdx.x;
  const int lane = t & 63;
  const int w = t >> 6;
  const int lg = lane >> 4;
  const int lr = lane & 15;
  const int b = blockIdx.x;

  // ---- stage B-fragments into LDS (16 KB, L2/L3-hot) ----
  {
    const f32x4* src = (const f32x4*)Bfrag;
    f32x4* dst = (f32x4*)bf_lds;
    #pragma unroll
    for (int i = 0; i < 4; ++i) dst[t + 256 * i] = src[t + 256 * i];
  }

  // ---- c[h] = Xi[b] . Wc[:,h], h = lane (2 accums to shorten fma chain) ----
  float c;
  {
    const float* xi = Xi + (size_t)b * DD;
    const float* wc = Wc + lane;
    float a0 = 0.f, a1 = 0.f;
    #pragma unroll 8
    for (int d = 0; d < DD; d += 2) {
      a0 = fmaf(xi[d], wc[d * HH], a0);
      a1 = fmaf(xi[d + 1], wc[(d + 1) * HH], a1);
    }
    c = a0 + a1;
  }
  float c4[4], z4[4];
  {
    const float zl = zv[lane];
    #pragma unroll
    for (int ct = 0; ct < 4; ++ct) {
      c4[ct] = __shfl(c, ct * 16 + lr, 64);
      z4[ct] = __shfl(zl, ct * 16 + lr, 64);
    }
  }
  const int mflag = *flagp;
  const float* xb = Xs + (size_t)b * (SS * DD) + lg * 8;
  const unsigned char* mbp = (const unsigned char*)maskv + (size_t)b * SS;
  const int* mip = (const int*)maskv + (size_t)b * SS;
  __syncthreads();

  const bf16x8* bp = (const bf16x8*)bf_lds;
  float part[4][8];
  #pragma unroll
  for (int kt = 0; kt < 4; ++kt)
    #pragma unroll
    for (int j = 0; j < 8; ++j) part[kt][j] = 0.f;
  float usum = 0.f, ssum = 0.f;

  #pragma unroll 1
  for (int tt = w; tt < NT; tt += 4) {
    const int srow = tt * 16 + lr;
    const int crow = (srow < SS) ? srow : (SS - 1);
    // mask (issued with the other loads; consumed late)
    int mv = (srow < SS) ? (mflag ? (int)mbp[crow] : mip[crow]) : 0;
    // X row segment loads
    const float* rp = xb + (size_t)crow * DD;
    f32x4 r0[4], r1[4];
    #pragma unroll
    for (int kt = 0; kt < 4; ++kt) {
      r0[kt] = *(const f32x4*)(rp + kt * 32);
      r1[kt] = *(const f32x4*)(rp + kt * 32 + 4);
    }
    // C-init from pre-swizzled P + c
    f32x4 acc[4];
    {
      const f32x4* pp = (const f32x4*)(Psw + (size_t)((tt * 4 + lg) * 16 + lr) * 16);
      #pragma unroll
      for (int ct = 0; ct < 4; ++ct) {
        const f32x4 pv = pp[ct];
        acc[ct][0] = pv[0] + c4[ct]; acc[ct][1] = pv[1] + c4[ct];
        acc[ct][2] = pv[2] + c4[ct]; acc[ct][3] = pv[3] + c4[ct];
      }
    }
    // convert to bf16 A-fragments
    bf16x8 af[4];
    #pragma unroll
    for (int kt = 0; kt < 4; ++kt) {
      bf16x8 v;
      v[0] = (__bf16)r0[kt][0]; v[1] = (__bf16)r0[kt][1];
      v[2] = (__bf16)r0[kt][2]; v[3] = (__bf16)r0[kt][3];
      v[4] = (__bf16)r1[kt][0]; v[5] = (__bf16)r1[kt][1];
      v[6] = (__bf16)r1[kt][2]; v[7] = (__bf16)r1[kt][3];
      af[kt] = v;
    }
    #pragma unroll
    for (int kt = 0; kt < 4; ++kt)
      #pragma unroll
      for (int ct = 0; ct < 4; ++ct)
        acc[ct] = __builtin_amdgcn_mfma_f32_16x16x32_bf16(af[kt], bp[(ct * 4 + kt) * 64 + lane],
                                                          acc[ct], 0, 0, 0);
    // scores[s=tt*16+4lg+r] = sum_h z[h]*tanh(pre); reduce over lr (h-groups)
    float sc[4];
    #pragma unroll
    for (int r = 0; r < 4; ++r) {
      float p = 0.f;
      #pragma unroll
      for (int ct = 0; ct < 4; ++ct) {
        const float e2 = __expf(2.f * acc[ct][r]);
        const float th = 1.f - 2.f * __builtin_amdgcn_rcpf(e2 + 1.f);
        p = fmaf(z4[ct], th, p);
      }
      p += __shfl_xor(p, 1);
      p += __shfl_xor(p, 2);
      p += __shfl_xor(p, 4);
      p += __shfl_xor(p, 8);
      sc[r] = p;      // full score, same across each 16-lane lr group
    }
    // lane needs score of row tt*16+lr (held by lane (lr>>2)*16, reg lr&3)
    #pragma unroll
    for (int r = 0; r < 4; ++r) sc[r] = __shfl(sc[r], (lr >> 2) << 4, 64);
    const float sa = (lr & 1) ? sc[1] : sc[0];
    const float sb = (lr & 1) ? sc[3] : sc[2];
    const float mysc = (lr & 2) ? sb : sa;
    const float u = mv ? __expf(mysc) : 0.f;   // |score| <= sum|z| ~ 7: no max-sub needed
    ssum += mv ? mysc : 0.f;
    usum += u;
    #pragma unroll
    for (int kt = 0; kt < 4; ++kt)
      #pragma unroll
      for (int j = 0; j < 8; ++j)
        part[kt][j] = fmaf(u, (float)af[kt][j], part[kt][j]);
  }

  // ---- reduce over the 16 lr lanes; write per-wave partials to LDS ----
  #pragma unroll
  for (int off = 1; off <= 8; off <<= 1) {
    #pragma unroll
    for (int kt = 0; kt < 4; ++kt)
      #pragma unroll
      for (int j = 0; j < 8; ++j)
        part[kt][j] += __shfl_xor(part[kt][j], off);
    usum += __shfl_xor(usum, off);
    ssum += __shfl_xor(ssum, off);
  }
  if (lr == 0) {
    #pragma unroll
    for (int kt = 0; kt < 4; ++kt)
      #pragma unroll
      for (int j = 0; j < 8; ++j)
        psum[w][kt * 32 + lg * 8 + j] = part[kt][j];
  }
  if (lane == 0) { uw[w] = usum; sw[w] = ssum; }
  __syncthreads();

  // ---- final combine: 129 threads write the output row ----
  if (t < DD) {
    const float num = psum[0][t] + psum[1][t] + psum[2][t] + psum[3][t];
    const float den = (uw[0] + uw[1]) + (uw[2] + uw[3]);
    out[(size_t)b * OUTW + t] = num / den;
  } else if (t == DD) {
    out[(size_t)b * OUTW + DD] = (sw[0] + sw[1]) + (sw[2] + sw[3]);
  }
}

extern "C" void kernel_launch(void* const* d_in, const int* in_sizes, int n_in,
                              void* d_out, int out_size, void* d_ws, size_t ws_size,
                              hipStream_t stream) {
  const float* Xs  = (const float*)d_in[0];   // X_series [B,S,D]
  const float* pos = (const float*)d_in[1];   // pos_series [S,D]
  const float* Xi  = (const float*)d_in[2];   // X_item [B,D]
  const void*  mk  = d_in[3];                 // valid_mask [B,S] (bool8 or int32 — probed)
  const float* Wc  = (const float*)d_in[4];
  const float* Wp  = (const float*)d_in[5];
  const float* We  = (const float*)d_in[6];
  const float* zv  = (const float*)d_in[7];
  float* out = (float*)d_out;

  char* ws = (char*)d_ws;
  int*   flag  = (int*)ws;                             // 4 B    @ 0
  float* Pmat  = (float*)(ws + 256);                   // 51200 B
  short* Bfrag = (short*)(ws + 256 + SS * HH * 4);     // 16384 B @ 51456
  float* Psw   = (float*)(ws + 256 + SS * HH * 4 + 16384);  // 53248 B @ 67840 (16B-aligned)

  setup_kernel<<<SS + 2, 256, 0, stream>>>(pos, Wp, We, mk, Pmat, Bfrag, flag);
  swizzle_kernel<<<NT, 256, 0, stream>>>(Pmat, Psw);
  fused_kernel<<<BB, 256, 0, stream>>>(Xs, Xi, mk, Wc, zv, Psw, Bfrag, flag, out);
}

// Round 7
// 241.353 us; speedup vs baseline: 1.1193x; 1.1193x over previous
//
#include <hip/hip_runtime.h>

#define BB 4096
#define SS 200
#define DD 128
#define HH 64
#define NT 13            // 13 tiles of 16 rows (208 padded)
#define OUTW (DD + 1)

typedef __attribute__((ext_vector_type(4))) float f32x4;
typedef __attribute__((ext_vector_type(8))) __bf16 bf16x8;

__device__ __forceinline__ short f2b(float f) {        // f32 -> bf16 (RNE)
  unsigned int u = __float_as_uint(f);
  unsigned int r = (u + 0x7FFFu + ((u >> 16) & 1u)) >> 16;
  return (short)r;
}

// DPP-based sum over the 16-lane row group (lanes lg*16..lg*16+15).
// All 16 lanes end up holding the full sum. VALU-pipe only (no LDS).
template <int CTRL>
__device__ __forceinline__ float dpp_add(float x) {
  int xi = __float_as_int(x);
  int yi = __builtin_amdgcn_update_dpp(xi, xi, CTRL, 0xF, 0xF, false);
  return x + __int_as_float(yi);
}
__device__ __forceinline__ float row16_sum(float x) {
  x = dpp_add<0xB1>(x);    // quad_perm(1,0,3,2): xor 1
  x = dpp_add<0x4E>(x);    // quad_perm(2,3,0,1): xor 2
  x = dpp_add<0x124>(x);   // row_ror:4
  x = dpp_add<0x128>(x);   // row_ror:8
  return x;
}

// ---------------- setup1: P = pos@Wp, We -> MFMA B-frag order, mask dtype probe ----
__global__ void setup_kernel(const float* __restrict__ pos,
                             const float* __restrict__ Wp,
                             const float* __restrict__ We,
                             const void* __restrict__ maskv,
                             float* __restrict__ Pmat,
                             short* __restrict__ Bfrag,
                             int* __restrict__ flag) {
  __shared__ int anyf[4];
  const int blk = blockIdx.x;
  const int t = threadIdx.x;
  if (blk < SS) {
    if (t < HH) {
      float acc = 0.f;
      #pragma unroll 8
      for (int d = 0; d < DD; ++d) acc = fmaf(pos[blk * DD + d], Wp[d * HH + t], acc);
      Pmat[blk * HH + t] = acc;
    }
  } else if (blk == SS) {
    // Bfrag[((ct*4+kt)*64+lane)*8 + j] = bf16(We[kt*32 + 8*(lane>>4) + j][ct*16 + (lane&15)])
    for (int id = t; id < 1024; id += 256) {
      int lane = id & 63;
      int kt = (id >> 6) & 3;
      int ct = id >> 8;
      int kbase = kt * 32 + 8 * (lane >> 4);
      int n = ct * 16 + (lane & 15);
      short* dst = Bfrag + id * 8;
      #pragma unroll
      for (int j = 0; j < 8; ++j) dst[j] = f2b(We[(kbase + j) * HH + n]);
    }
  } else {
    // mask dtype probe: bool8 has nonzero bytes at positions %4!=0; int32(0/1) does not
    const unsigned char* mb = (const unsigned char*)maskv;
    int local = 0;
    for (int i = t; i < 4096; i += 256)
      if ((i & 3) != 0 && mb[i] != 0) local = 1;
    unsigned long long bal = __ballot(local != 0);
    if ((t & 63) == 0) anyf[t >> 6] = (bal != 0ull) ? 1 : 0;
    __syncthreads();
    if (t == 0) *flag = (anyf[0] | anyf[1] | anyf[2] | anyf[3]);
  }
}

// ---------------- setup2: swizzle Pmat into per-lane-contiguous layout -------------
// Psw[(((t*4+lg)*16+lr)*16 + ct*4 + r)] = Pmat[min(t*16+4lg+r,199)][16ct+lr]
__global__ void swizzle_kernel(const float* __restrict__ Pmat, float* __restrict__ Psw) {
  const int t = blockIdx.x;                 // tile 0..12
  const int tid = threadIdx.x;              // 256
  const int lg = tid >> 6, lr = (tid >> 2) & 15, ct = tid & 3;
  f32x4 v;
  #pragma unroll
  for (int r = 0; r < 4; ++r) {
    int s = t * 16 + 4 * lg + r;
    if (s >= SS) s = SS - 1;
    v[r] = Pmat[s * HH + ct * 16 + lr];
  }
  *(f32x4*)&Psw[((t * 4 + lg) * 16 + lr) * 16 + ct * 4] = v;
}

// ---------------- fused: one WAVE per batch row; DPP epilogue, prefetch ILP --------
__global__ __launch_bounds__(256, 3) void fused_kernel(
    const float* __restrict__ Xs, const float* __restrict__ Xi,
    const void* __restrict__ maskv, const float* __restrict__ Wc,
    const float* __restrict__ zv, const float* __restrict__ Psw,
    const short* __restrict__ Bfrag, const int* __restrict__ flagp,
    float* __restrict__ out) {
  __shared__ __align__(16) short bf_lds[16 * 64 * 8];   // 16 KB We B-fragments

  const int t = threadIdx.x;
  const int lane = t & 63;
  const int w = t >> 6;
  const int lg = lane >> 4;
  const int lr = lane & 15;
  const int b = blockIdx.x * 4 + w;

  const float* xb = Xs + (size_t)b * (SS * DD) + lg * 8;

  // ---- issue tile-0 X loads + Psw tile-0 FIRST (latency hides under setup) ----
  f32x4 raw[8];
  {
    const float* rp = xb + (size_t)lr * DD;
    #pragma unroll
    for (int kt = 0; kt < 4; ++kt) {
      raw[2 * kt]     = *(const f32x4*)(rp + kt * 32);
      raw[2 * kt + 1] = *(const f32x4*)(rp + kt * 32 + 4);
    }
  }
  f32x4 pswr[4];
  {
    const f32x4* pp = (const f32x4*)(Psw + (size_t)(lg * 16 + lr) * 16);
    #pragma unroll
    for (int ct = 0; ct < 4; ++ct) pswr[ct] = pp[ct];
  }

  // ---- stage B-fragments into LDS (16 KB, L2/L3-hot) ----
  {
    const f32x4* src = (const f32x4*)Bfrag;
    f32x4* dst = (f32x4*)bf_lds;
    #pragma unroll
    for (int i = 0; i < 4; ++i) dst[t + 256 * i] = src[t + 256 * i];
  }

  // ---- c[h] = Xi[b] . Wc[:,h], h = lane; redistribute c,z to (ct,lr) layout ----
  float c = 0.f;
  {
    const float* xi = Xi + (size_t)b * DD;
    const float* wc = Wc + lane;
    #pragma unroll 8
    for (int d = 0; d < DD; ++d) c = fmaf(xi[d], wc[d * HH], c);
  }

  // ---- per-lane mask bits: bit tt = valid_mask[b][tt*16+lr] ----
  const int mflag = *flagp;
  unsigned mbits = 0;
  if (mflag) {
    const unsigned char* mbp = (const unsigned char*)maskv + (size_t)b * SS;
    #pragma unroll
    for (int tt = 0; tt < NT; ++tt) {
      const int srow = tt * 16 + lr;
      unsigned v = (srow < SS) ? (unsigned)mbp[srow] : 0u;
      mbits |= (v ? 1u : 0u) << tt;
    }
  } else {
    const int* mip = (const int*)maskv + (size_t)b * SS;
    #pragma unroll
    for (int tt = 0; tt < NT; ++tt) {
      const int srow = tt * 16 + lr;
      unsigned v = (srow < SS) ? (unsigned)(mip[srow] != 0) : 0u;
      mbits |= v << tt;
    }
  }

  float c4[4], z4[4];
  {
    const float zl = zv[lane];
    #pragma unroll
    for (int ct = 0; ct < 4; ++ct) {
      c4[ct] = __shfl(c, ct * 16 + lr, 64);
      z4[ct] = __shfl(zl, ct * 16 + lr, 64);
    }
  }
  __syncthreads();

  const bf16x8* bp = (const bf16x8*)bf_lds;
  float part[4][8];
  #pragma unroll
  for (int kt = 0; kt < 4; ++kt)
    #pragma unroll
    for (int j = 0; j < 8; ++j) part[kt][j] = 0.f;
  float usum = 0.f, ssum = 0.f;

  for (int tt = 0; tt < NT; ++tt) {
    // ---- consume prefetched raw/pswr (single vmcnt drain per tile) ----
    bf16x8 af[4];
    #pragma unroll
    for (int kt = 0; kt < 4; ++kt) {
      bf16x8 v;
      v[0] = (__bf16)raw[2*kt][0]; v[1] = (__bf16)raw[2*kt][1];
      v[2] = (__bf16)raw[2*kt][2]; v[3] = (__bf16)raw[2*kt][3];
      v[4] = (__bf16)raw[2*kt+1][0]; v[5] = (__bf16)raw[2*kt+1][1];
      v[6] = (__bf16)raw[2*kt+1][2]; v[7] = (__bf16)raw[2*kt+1][3];
      af[kt] = v;
    }
    f32x4 acc[4];
    #pragma unroll
    for (int ct = 0; ct < 4; ++ct) {
      const f32x4 pv = pswr[ct];
      acc[ct][0] = pv[0] + c4[ct]; acc[ct][1] = pv[1] + c4[ct];
      acc[ct][2] = pv[2] + c4[ct]; acc[ct][3] = pv[3] + c4[ct];
    }
    // ---- prefetch tile t+1 (consumed ONLY next iteration) ----
    if (tt + 1 < NT) {
      int srow = (tt + 1) * 16 + lr;
      if (srow >= SS) srow = SS - 1;                 // clamped rows masked via mbits
      const float* rp = xb + (size_t)srow * DD;
      #pragma unroll
      for (int kt = 0; kt < 4; ++kt) {
        raw[2 * kt]     = *(const f32x4*)(rp + kt * 32);
        raw[2 * kt + 1] = *(const f32x4*)(rp + kt * 32 + 4);
      }
      const f32x4* pp = (const f32x4*)(Psw + (size_t)(((tt + 1) * 4 + lg) * 16 + lr) * 16);
      #pragma unroll
      for (int ct = 0; ct < 4; ++ct) pswr[ct] = pp[ct];
    }
    // ---- compute: MFMA + score epilogue (no VMEM from here to loop end) ----
    #pragma unroll
    for (int kt = 0; kt < 4; ++kt)
      #pragma unroll
      for (int ct = 0; ct < 4; ++ct)
        acc[ct] = __builtin_amdgcn_mfma_f32_16x16x32_bf16(af[kt], bp[(ct * 4 + kt) * 64 + lane],
                                                          acc[ct], 0, 0, 0);
    // scores[s=tt*16+4lg+r] = sum_h z[h]*tanh(pre); DPP row-sum over the 16 lr lanes
    float sc[4];
    #pragma unroll
    for (int r = 0; r < 4; ++r) {
      float p = 0.f;
      #pragma unroll
      for (int ct = 0; ct < 4; ++ct) {
        const float e2 = __expf(2.f * acc[ct][r]);
        const float th = 1.f - 2.f * __builtin_amdgcn_rcpf(e2 + 1.f);
        p = fmaf(z4[ct], th, p);
      }
      sc[r] = row16_sum(p);       // all 16 lanes of group lg hold score(s=tt*16+4lg+r)
    }
    // redistribute: lane (lg,lr) needs score of row tt*16+lr, held by group lr>>2.
    // pre-select sc[lr&3] locally, then ONE bpermute from lane ((lr>>2)<<4)|lr.
    const float s01 = (lr & 1) ? sc[1] : sc[0];
    const float s23 = (lr & 1) ? sc[3] : sc[2];
    const float sel = (lr & 2) ? s23 : s01;
    const float mysc = __shfl(sel, ((lr >> 2) << 4) | lr, 64);
    const bool mv = (mbits >> tt) & 1u;
    const float u = mv ? __expf(mysc) : 0.f;    // |score| <= sum|z| ~ 7: no max-sub needed
    ssum += mv ? mysc : 0.f;
    usum += u;
    #pragma unroll
    for (int kt = 0; kt < 4; ++kt)
      #pragma unroll
      for (int j = 0; j < 8; ++j)
        part[kt][j] = fmaf(u, (float)af[kt][j], part[kt][j]);
  }

  // ---- reduce over the 16 lr lanes (rows) via DPP; each lg group = distinct cols ----
  #pragma unroll
  for (int kt = 0; kt < 4; ++kt)
    #pragma unroll
    for (int j = 0; j < 8; ++j)
      part[kt][j] = row16_sum(part[kt][j]);
  usum = row16_sum(usum);
  ssum = row16_sum(ssum);

  const float inv = 1.f / usum;
  if (lr == 0) {
    float* ob = out + (size_t)b * OUTW;
    #pragma unroll
    for (int kt = 0; kt < 4; ++kt)
      #pragma unroll
      for (int j = 0; j < 8; ++j)
        ob[kt * 32 + lg * 8 + j] = part[kt][j] * inv;
  }
  if (lane == 8) out[(size_t)b * OUTW + DD] = ssum;
}

extern "C" void kernel_launch(void* const* d_in, const int* in_sizes, int n_in,
                              void* d_out, int out_size, void* d_ws, size_t ws_size,
                              hipStream_t stream) {
  const float* Xs  = (const float*)d_in[0];   // X_series [B,S,D]
  const float* pos = (const float*)d_in[1];   // pos_series [S,D]
  const float* Xi  = (const float*)d_in[2];   // X_item [B,D]
  const void*  mk  = d_in[3];                 // valid_mask [B,S] (bool8 or int32 — probed)
  const float* Wc  = (const float*)d_in[4];
  const float* Wp  = (const float*)d_in[5];
  const float* We  = (const float*)d_in[6];
  const float* zv  = (const float*)d_in[7];
  float* out = (float*)d_out;

  char* ws = (char*)d_ws;
  int*   flag  = (int*)ws;                             // 4 B    @ 0
  float* Pmat  = (float*)(ws + 256);                   // 51200 B
  short* Bfrag = (short*)(ws + 256 + SS * HH * 4);     // 16384 B @ 51456
  float* Psw   = (float*)(ws + 256 + SS * HH * 4 + 16384);  // 53248 B @ 67840 (16B-aligned)

  setup_kernel<<<SS + 2, 256, 0, stream>>>(pos, Wp, We, mk, Pmat, Bfrag, flag);
  swizzle_kernel<<<NT, 256, 0, stream>>>(Pmat, Psw);
  fused_kernel<<<BB / 4, 256, 0, stream>>>(Xs, Xi, mk, Wc, zv, Psw, Bfrag, flag, out);
}

// Round 8
// 187.431 us; speedup vs baseline: 1.4414x; 1.2877x over previous
//
#include <hip/hip_runtime.h>

#define BB 4096
#define SS 200
#define DD 128
#define HH 64
#define NT 13            // 13 tiles of 16 rows (208 padded)
#define OUTW (DD + 1)

// combined LDS: Bfrag (8192 shorts) + PswB (13*2*64*8 = 13312 shorts)
#define NCOMB (8192 + NT * 1024)          // 21504 shorts = 43008 B
#define NCVEC (NCOMB / 8)                 // 2688 f32x4 copies

typedef __attribute__((ext_vector_type(4))) float f32x4;
typedef __attribute__((ext_vector_type(8))) __bf16 bf16x8;

__device__ __forceinline__ short f2b(float f) {        // f32 -> bf16 (RNE)
  unsigned int u = __float_as_uint(f);
  unsigned int r = (u + 0x7FFFu + ((u >> 16) & 1u)) >> 16;
  return (short)r;
}

// DPP sum over each 16-lane group; all 16 lanes end with the group total.
template <int CTRL>
__device__ __forceinline__ float dpp_add(float x) {
  int xi = __float_as_int(x);
  int yi = __builtin_amdgcn_update_dpp(xi, xi, CTRL, 0xF, 0xF, false);
  return x + __int_as_float(yi);
}
__device__ __forceinline__ float row16_sum(float x) {
  x = dpp_add<0xB1>(x);    // quad_perm xor1
  x = dpp_add<0x4E>(x);    // quad_perm xor2
  x = dpp_add<0x124>(x);   // row_ror:4
  x = dpp_add<0x128>(x);   // row_ror:8
  return x;
}

// ---------------- setup1: P = pos@Wp, We -> MFMA B-frag order, mask dtype probe ----
__global__ void setup_kernel(const float* __restrict__ pos,
                             const float* __restrict__ Wp,
                             const float* __restrict__ We,
                             const void* __restrict__ maskv,
                             float* __restrict__ Pmat,
                             short* __restrict__ Bfrag,
                             int* __restrict__ flag) {
  __shared__ int anyf[4];
  const int blk = blockIdx.x;
  const int t = threadIdx.x;
  if (blk < SS) {
    if (t < HH) {
      float acc = 0.f;
      #pragma unroll 8
      for (int d = 0; d < DD; ++d) acc = fmaf(pos[blk * DD + d], Wp[d * HH + t], acc);
      Pmat[blk * HH + t] = acc;
    }
  } else if (blk == SS) {
    // Bfrag[((ct*4+kt)*64+lane)*8 + j] = bf16(We[kt*32 + 8*(lane>>4) + j][ct*16 + (lane&15)])
    for (int id = t; id < 1024; id += 256) {
      int lane = id & 63;
      int kt = (id >> 6) & 3;
      int ct = id >> 8;
      int kbase = kt * 32 + 8 * (lane >> 4);
      int n = ct * 16 + (lane & 15);
      short* dst = Bfrag + id * 8;
      #pragma unroll
      for (int j = 0; j < 8; ++j) dst[j] = f2b(We[(kbase + j) * HH + n]);
    }
  } else {
    // mask dtype probe: bool8 has nonzero bytes at positions %4!=0; int32(0/1) does not
    const unsigned char* mb = (const unsigned char*)maskv;
    int local = 0;
    for (int i = t; i < 4096; i += 256)
      if ((i & 3) != 0 && mb[i] != 0) local = 1;
    unsigned long long bal = __ballot(local != 0);
    if ((t & 63) == 0) anyf[t >> 6] = (bal != 0ull) ? 1 : 0;
    __syncthreads();
    if (t == 0) *flag = (anyf[0] | anyf[1] | anyf[2] | anyf[3]);
  }
}

// ---------------- setup2: Pmat -> bf16, per-lane MFMA-acc layout -------------------
// PswB[((tile*2+half)*64 + lane)*8 + e] = bf16(P[tile*16 + (lane>>4)*4 + (e&3),
//                                               (half*2 + (e>>2))*16 + (lane&15)])
__global__ void swizzle_kernel(const float* __restrict__ Pmat, short* __restrict__ PswB) {
  const int tile = blockIdx.x;              // 0..12
  const int tid = threadIdx.x;              // 128
  const int half = tid >> 6, lane = tid & 63;
  short* dst = PswB + ((size_t)(tile * 2 + half) * 64 + lane) * 8;
  #pragma unroll
  for (int e = 0; e < 8; ++e) {
    const int ct = (half << 1) | (e >> 2);
    const int r = e & 3;
    int s = tile * 16 + ((lane >> 4) << 2) + r;
    if (s >= SS) s = SS - 1;
    dst[e] = f2b(Pmat[s * HH + ct * 16 + (lane & 15)]);
  }
}

// ---------------- fused: one WAVE per row; no-spill streaming; P from LDS ----------
__global__ __launch_bounds__(256, 3) void fused_kernel(
    const float* __restrict__ Xs, const float* __restrict__ Xi,
    const void* __restrict__ maskv, const float* __restrict__ Wc,
    const float* __restrict__ zv,
    const short* __restrict__ Comb,    // Bfrag (8192) + PswB (13312), contiguous
    const int* __restrict__ flagp,
    float* __restrict__ out) {
  __shared__ __align__(16) short comb_lds[NCOMB];   // 43008 B

  const int t = threadIdx.x;
  const int lane = t & 63;
  const int w = t >> 6;
  const int lg = lane >> 4;
  const int lr = lane & 15;
  const int b = blockIdx.x * 4 + w;

  const float* xb = Xs + (size_t)b * (SS * DD) + lg * 8;

  // ---- issue tile-0 X loads FIRST (latency hides under staging/setup) ----
  f32x4 raw[8];
  {
    const float* rp = xb + (size_t)lr * DD;
    #pragma unroll
    for (int kt = 0; kt < 4; ++kt) {
      raw[2 * kt]     = *(const f32x4*)(rp + kt * 32);
      raw[2 * kt + 1] = *(const f32x4*)(rp + kt * 32 + 4);
    }
  }

  // ---- stage Bfrag + PswB into LDS (43 KB, L2/L3-hot) ----
  {
    const f32x4* src = (const f32x4*)Comb;
    f32x4* dst = (f32x4*)comb_lds;
    #pragma unroll
    for (int i = 0; i < 11; ++i) {
      const int idx = t + 256 * i;
      if (idx < NCVEC) dst[idx] = src[idx];
    }
  }

  // ---- c[h] = Xi[b] . Wc[:,h], h = lane ----
  float c = 0.f;
  {
    const float* xi = Xi + (size_t)b * DD;
    const float* wc = Wc + lane;
    #pragma unroll 8
    for (int d = 0; d < DD; ++d) c = fmaf(xi[d], wc[d * HH], c);
  }

  // ---- per-lane mask bits: bit tt = valid_mask[b][tt*16+lr] ----
  const int mflag = *flagp;
  unsigned mbits = 0;
  if (mflag) {
    const unsigned char* mbp = (const unsigned char*)maskv + (size_t)b * SS;
    #pragma unroll
    for (int tt = 0; tt < NT; ++tt) {
      const int srow = tt * 16 + lr;
      unsigned v = (srow < SS) ? (unsigned)mbp[srow] : 0u;
      mbits |= (v ? 1u : 0u) << tt;
    }
  } else {
    const int* mip = (const int*)maskv + (size_t)b * SS;
    #pragma unroll
    for (int tt = 0; tt < NT; ++tt) {
      const int srow = tt * 16 + lr;
      unsigned v = (srow < SS) ? (unsigned)(mip[srow] != 0) : 0u;
      mbits |= v << tt;
    }
  }

  float c4[4], z4[4];
  {
    const float zl = zv[lane];
    #pragma unroll
    for (int ct = 0; ct < 4; ++ct) {
      c4[ct] = __shfl(c, ct * 16 + lr, 64);
      z4[ct] = __shfl(zl, ct * 16 + lr, 64);
    }
  }
  __syncthreads();

  const bf16x8* bp = (const bf16x8*)comb_lds;                 // B-fragments
  const bf16x8* pswl = (const bf16x8*)(comb_lds + 8192);      // P tiles (bf16)
  float part[4][8];
  #pragma unroll
  for (int kt = 0; kt < 4; ++kt)
    #pragma unroll
    for (int j = 0; j < 8; ++j) part[kt][j] = 0.f;
  float usum = 0.f, ssum = 0.f;

  for (int tt = 0; tt < NT; ++tt) {
    // ---- consume prefetched raw (the only cross-iteration VMEM dependency) ----
    bf16x8 af[4];
    #pragma unroll
    for (int kt = 0; kt < 4; ++kt) {
      bf16x8 v;
      v[0] = (__bf16)raw[2*kt][0]; v[1] = (__bf16)raw[2*kt][1];
      v[2] = (__bf16)raw[2*kt][2]; v[3] = (__bf16)raw[2*kt][3];
      v[4] = (__bf16)raw[2*kt+1][0]; v[5] = (__bf16)raw[2*kt+1][1];
      v[6] = (__bf16)raw[2*kt+1][2]; v[7] = (__bf16)raw[2*kt+1][3];
      af[kt] = v;
    }
    // ---- prefetch tile t+1 (consumed ONLY next iteration) ----
    if (tt + 1 < NT) {
      int srow = (tt + 1) * 16 + lr;
      if (srow >= SS) srow = SS - 1;                 // clamped rows masked via mbits
      const float* rp = xb + (size_t)srow * DD;
      #pragma unroll
      for (int kt = 0; kt < 4; ++kt) {
        raw[2 * kt]     = *(const f32x4*)(rp + kt * 32);
        raw[2 * kt + 1] = *(const f32x4*)(rp + kt * 32 + 4);
      }
    }
    // ---- C-init from LDS P (bf16) + c; no VMEM from here to loop end ----
    const bf16x8 p0 = pswl[tt * 128 + lane];
    const bf16x8 p1 = pswl[tt * 128 + 64 + lane];
    f32x4 acc[4];
    #pragma unroll
    for (int ct = 0; ct < 4; ++ct) {
      #pragma unroll
      for (int r = 0; r < 4; ++r) {
        const float pv = (ct < 2) ? (float)p0[ct * 4 + r] : (float)p1[(ct - 2) * 4 + r];
        acc[ct][r] = pv + c4[ct];
      }
    }
    #pragma unroll
    for (int kt = 0; kt < 4; ++kt)
      #pragma unroll
      for (int ct = 0; ct < 4; ++ct)
        acc[ct] = __builtin_amdgcn_mfma_f32_16x16x32_bf16(af[kt], bp[(ct * 4 + kt) * 64 + lane],
                                                          acc[ct], 0, 0, 0);
    // scores[s=tt*16+4lg+r] = sum_h z[h]*tanh(pre); DPP row-sum over the 16 lr lanes
    float sc[4];
    #pragma unroll
    for (int r = 0; r < 4; ++r) {
      float p = 0.f;
      #pragma unroll
      for (int ct = 0; ct < 4; ++ct) {
        const float e2 = __expf(2.f * acc[ct][r]);
        const float th = 1.f - 2.f * __builtin_amdgcn_rcpf(e2 + 1.f);
        p = fmaf(z4[ct], th, p);
      }
      sc[r] = row16_sum(p);       // all 16 lanes of group lg hold score(s=tt*16+4lg+r)
    }
    // redistribute: lane (lg,lr) needs score of row tt*16+lr, held by group lr>>2.
    const float s01 = (lr & 1) ? sc[1] : sc[0];
    const float s23 = (lr & 1) ? sc[3] : sc[2];
    const float sel = (lr & 2) ? s23 : s01;
    const float mysc = __shfl(sel, ((lr >> 2) << 4) | lr, 64);
    const bool mv = (mbits >> tt) & 1u;
    const float u = mv ? __expf(mysc) : 0.f;    // |score| <= sum|z| ~ 7: no max-sub needed
    ssum += mv ? mysc : 0.f;
    usum += u;
    #pragma unroll
    for (int kt = 0; kt < 4; ++kt)
      #pragma unroll
      for (int j = 0; j < 8; ++j)
        part[kt][j] = fmaf(u, (float)af[kt][j], part[kt][j]);
  }

  // ---- reduce over the 16 lr lanes (rows) via DPP; each lg group = distinct cols ----
  #pragma unroll
  for (int kt = 0; kt < 4; ++kt)
    #pragma unroll
    for (int j = 0; j < 8; ++j)
      part[kt][j] = row16_sum(part[kt][j]);
  usum = row16_sum(usum);
  ssum = row16_sum(ssum);

  const float inv = 1.f / usum;
  if (lr == 0) {
    float* ob = out + (size_t)b * OUTW;
    #pragma unroll
    for (int kt = 0; kt < 4; ++kt)
      #pragma unroll
      for (int j = 0; j < 8; ++j)
        ob[kt * 32 + lg * 8 + j] = part[kt][j] * inv;
  }
  if (lane == 8) out[(size_t)b * OUTW + DD] = ssum;
}

extern "C" void kernel_launch(void* const* d_in, const int* in_sizes, int n_in,
                              void* d_out, int out_size, void* d_ws, size_t ws_size,
                              hipStream_t stream) {
  const float* Xs  = (const float*)d_in[0];   // X_series [B,S,D]
  const float* pos = (const float*)d_in[1];   // pos_series [S,D]
  const float* Xi  = (const float*)d_in[2];   // X_item [B,D]
  const void*  mk  = d_in[3];                 // valid_mask [B,S] (bool8 or int32 — probed)
  const float* Wc  = (const float*)d_in[4];
  const float* Wp  = (const float*)d_in[5];
  const float* We  = (const float*)d_in[6];
  const float* zv  = (const float*)d_in[7];
  float* out = (float*)d_out;

  char* ws = (char*)d_ws;
  int*   flag  = (int*)ws;                             // 4 B     @ 0
  float* Pmat  = (float*)(ws + 256);                   // 51200 B @ 256
  short* Bfrag = (short*)(ws + 256 + SS * HH * 4);     // 16384 B @ 51456
  short* PswB  = (short*)(ws + 256 + SS * HH * 4 + 16384); // 26624 B @ 67840 (contiguous!)

  setup_kernel<<<SS + 2, 256, 0, stream>>>(pos, Wp, We, mk, Pmat, Bfrag, flag);
  swizzle_kernel<<<NT, 128, 0, stream>>>(Pmat, PswB);
  fused_kernel<<<BB / 4, 256, 0, stream>>>(Xs, Xi, mk, Wc, zv, Bfrag, flag, out);
}